// Round 7
// baseline (597.713 us; speedup 1.0000x reference)
//
#include <hip/hip_runtime.h>
#include <hip/hip_cooperative_groups.h>
#include <hip/hip_fp16.h>
#include <math.h>

namespace cg = cooperative_groups;

#define DIM      32
#define HDIM     16                // DIM/2 float2 / half2 pairs per row
#define N_NODES  100000
#define N_EDGES  1600000
#define L0       0.1f

#define COOP_BLOCKS   2048         // 8 blocks/CU x 256 CUs, fully co-resident
#define COOP_THREADS  256

// ===========================================================================
// R6 post-mortem: dedup structures execute worse than R0's edge loop despite
// halved bytes (R5/R6 both ~310us at 40% VALU vs R0's 203us at 62%).  The
// remaining cheap win is the ~63us of non-kernel time in the R0 path (memset
// dispatch + convert dispatch + ~10-17us/dispatch overhead).  R7: single
// cooperative dispatch = zero(ws) -> grid.sync -> R0 edge loop (byte-
// identical math/atomics) -> grid.sync -> convert.  Fallback to the proven
// 3-dispatch path if cooperative launch is unavailable.
// ===========================================================================
__global__ __launch_bounds__(256, 8) void fused_coop_kernel(
    const float*  __restrict__ x,
    const int*    __restrict__ edges,
    __half2*      __restrict__ grad_h,     // N_NODES*HDIM half2 (ws)
    float*        __restrict__ energy_ws,  // 1 float (ws)
    float*        __restrict__ out)
{
    cg::grid_group grid = cg::this_grid();

    const int tid  = threadIdx.x;
    const int gtid = blockIdx.x * COOP_THREADS + tid;
    const int nthr = gridDim.x * COOP_THREADS;

    // ---- Phase A: zero the f16 accumulator + energy slot (6.4 MB) ----
    {
        uint4* g4 = (uint4*)grad_h;
        const int n4 = N_NODES * HDIM / 4;           // 400,000 uint4
        for (int i = gtid; i < n4; i += nthr)
            g4[i] = make_uint4(0u, 0u, 0u, 0u);
        if (gtid == 0) *energy_ws = 0.0f;
    }
    grid.sync();

    // ---- Phase B: R0 edge kernel, token-identical math & atomic pipe ----
    {
        const int lane  = tid & 63;
        const int k     = lane & 15;        // float2 pair index 0..15
        const int quad  = lane >> 4;        // which of the wave's 4 edges
        const int qId   = ((blockIdx.x * blockDim.x + tid) >> 6) * 4 + quad;
        const int nQuad = ((gridDim.x * blockDim.x) >> 6) * 4;

        const float2* __restrict__ x2 = (const float2*)x;
        const float Jx = (k == 0) ? -1.0f : 1.0f;

        double energy = 0.0;

        for (int e0 = qId; e0 < N_EDGES; e0 += 2 * nQuad) {
            const int  e1 = e0 + nQuad;
            const bool a1 = (e1 < N_EDGES);

            const int2 ev0 = ((const int2*)edges)[e0];
            const int2 ev1 = a1 ? ((const int2*)edges)[e1] : make_int2(0, 0);
            const float2 xu0 = x2[ev0.x * HDIM + k];
            const float2 xv0 = x2[ev0.y * HDIM + k];
            const float2 xu1 = x2[ev1.x * HDIM + k];
            const float2 xv1 = x2[ev1.y * HDIM + k];

            float p0 = Jx * xu0.x * xv0.x + xu0.y * xv0.y;
            float p1 = Jx * xu1.x * xv1.x + xu1.y * xv1.y;
            #pragma unroll
            for (int off = 8; off; off >>= 1) {
                p0 += __shfl_xor(p0, off, 16);
                p1 += __shfl_xor(p1, off, 16);
            }

            {
                const float inner = fminf(p0, -1.0000001f);
                const float zm1   = -inner - 1.0f;
                const float s     = sqrtf(zm1 * (zm1 + 2.0f));
                const float dist  = log1pf(zm1 + s);
                const float delta = dist - L0;
                const float f     = -delta / (s + 1e-9f);
                unsafeAtomicAdd(&grad_h[ev0.x * HDIM + k],
                                __floats2half2_rn(f * Jx * xv0.x, f * xv0.y));
                unsafeAtomicAdd(&grad_h[ev0.y * HDIM + k],
                                __floats2half2_rn(f * Jx * xu0.x, f * xu0.y));
                if (k == 0) energy += 0.5 * (double)delta * (double)delta;
            }
            if (a1) {
                const float inner = fminf(p1, -1.0000001f);
                const float zm1   = -inner - 1.0f;
                const float s     = sqrtf(zm1 * (zm1 + 2.0f));
                const float dist  = log1pf(zm1 + s);
                const float delta = dist - L0;
                const float f     = -delta / (s + 1e-9f);
                unsafeAtomicAdd(&grad_h[ev1.x * HDIM + k],
                                __floats2half2_rn(f * Jx * xv1.x, f * xv1.y));
                unsafeAtomicAdd(&grad_h[ev1.y * HDIM + k],
                                __floats2half2_rn(f * Jx * xu1.x, f * xu1.y));
                if (k == 0) energy += 0.5 * (double)delta * (double)delta;
            }
        }

        #pragma unroll
        for (int off = 32; off; off >>= 1)
            energy += __shfl_xor(energy, off, 64);

        __shared__ double s_e[4];
        if (lane == 0) s_e[tid >> 6] = energy;
        __syncthreads();
        if (tid == 0)
            atomicAdd(energy_ws,
                      (float)(s_e[0] + s_e[1] + s_e[2] + s_e[3]));
    }
    grid.sync();

    // ---- Phase C: f16 ws -> f32 grad + energy publish ----
    {
        const int lim = N_NODES * HDIM;
        for (int i = gtid; i < lim; i += nthr) {
            const float2 f = __half22float2(grad_h[i]);
            out[1 + 2 * i]     = f.x;
            out[1 + 2 * i + 1] = f.y;
        }
        if (gtid == 0) out[0] = *energy_ws;
    }
}

// ===========================================================================
// Fallback 1 (3 dispatches): round-0 f16-packed-atomic path, proven 266 us.
// ===========================================================================
__global__ __launch_bounds__(256) void spring_edge_f16_kernel(
    const float*  __restrict__ x,
    const int*    __restrict__ edges,
    __half2*      __restrict__ grad_h,
    float*        __restrict__ energy_ws)
{
    const int tid   = threadIdx.x;
    const int lane  = tid & 63;
    const int k     = lane & 15;
    const int quad  = lane >> 4;
    const int qId   = ((blockIdx.x * blockDim.x + tid) >> 6) * 4 + quad;
    const int nQuad = ((gridDim.x * blockDim.x) >> 6) * 4;

    const float2* __restrict__ x2 = (const float2*)x;
    const float Jx = (k == 0) ? -1.0f : 1.0f;

    double energy = 0.0;

    for (int e0 = qId; e0 < N_EDGES; e0 += 2 * nQuad) {
        const int  e1 = e0 + nQuad;
        const bool a1 = (e1 < N_EDGES);

        const int2 ev0 = ((const int2*)edges)[e0];
        const int2 ev1 = a1 ? ((const int2*)edges)[e1] : make_int2(0, 0);
        const float2 xu0 = x2[ev0.x * HDIM + k];
        const float2 xv0 = x2[ev0.y * HDIM + k];
        const float2 xu1 = x2[ev1.x * HDIM + k];
        const float2 xv1 = x2[ev1.y * HDIM + k];

        float p0 = Jx * xu0.x * xv0.x + xu0.y * xv0.y;
        float p1 = Jx * xu1.x * xv1.x + xu1.y * xv1.y;
        #pragma unroll
        for (int off = 8; off; off >>= 1) {
            p0 += __shfl_xor(p0, off, 16);
            p1 += __shfl_xor(p1, off, 16);
        }

        {
            const float inner = fminf(p0, -1.0000001f);
            const float zm1   = -inner - 1.0f;
            const float s     = sqrtf(zm1 * (zm1 + 2.0f));
            const float dist  = log1pf(zm1 + s);
            const float delta = dist - L0;
            const float f     = -delta / (s + 1e-9f);
            unsafeAtomicAdd(&grad_h[ev0.x * HDIM + k],
                            __floats2half2_rn(f * Jx * xv0.x, f * xv0.y));
            unsafeAtomicAdd(&grad_h[ev0.y * HDIM + k],
                            __floats2half2_rn(f * Jx * xu0.x, f * xu0.y));
            if (k == 0) energy += 0.5 * (double)delta * (double)delta;
        }
        if (a1) {
            const float inner = fminf(p1, -1.0000001f);
            const float zm1   = -inner - 1.0f;
            const float s     = sqrtf(zm1 * (zm1 + 2.0f));
            const float dist  = log1pf(zm1 + s);
            const float delta = dist - L0;
            const float f     = -delta / (s + 1e-9f);
            unsafeAtomicAdd(&grad_h[ev1.x * HDIM + k],
                            __floats2half2_rn(f * Jx * xv1.x, f * xv1.y));
            unsafeAtomicAdd(&grad_h[ev1.y * HDIM + k],
                            __floats2half2_rn(f * Jx * xu1.x, f * xu1.y));
            if (k == 0) energy += 0.5 * (double)delta * (double)delta;
        }
    }

    #pragma unroll
    for (int off = 32; off; off >>= 1)
        energy += __shfl_xor(energy, off, 64);

    __shared__ double s_e[4];
    if (lane == 0) s_e[tid >> 6] = energy;
    __syncthreads();
    if (tid == 0)
        atomicAdd(energy_ws, (float)(s_e[0] + s_e[1] + s_e[2] + s_e[3]));
}

__global__ __launch_bounds__(256) void convert_kernel(
    const __half2* __restrict__ grad_h,
    const float*   __restrict__ energy_ws,
    float*         __restrict__ out)
{
    const int i = blockIdx.x * 256 + threadIdx.x;
    if (i < N_NODES * HDIM) {
        const float2 f = __half22float2(grad_h[i]);
        out[1 + 2 * i]     = f.x;
        out[1 + 2 * i + 1] = f.y;
    }
    if (i == 0) out[0] = *energy_ws;
}

// ===========================================================================
// Fallback 2 (no usable ws): known-correct fused kernel.
// ===========================================================================
__global__ __launch_bounds__(256) void spring_edge_kernel(
    const float* __restrict__ x,
    const int*   __restrict__ edges,
    float*       __restrict__ out)
{
    const int tid    = threadIdx.x;
    const int lane   = tid & 63;
    const int d      = lane & 31;
    const int half   = lane >> 5;
    const int waveId = (blockIdx.x * blockDim.x + tid) >> 6;
    const int nWaves = (gridDim.x * blockDim.x) >> 6;

    float* __restrict__ grad = out + 1;
    const float Jd = (d == 0) ? -1.0f : 1.0f;
    double energy = 0.0;

    for (int e0 = waveId * 2; e0 < N_EDGES; e0 += nWaves * 2) {
        const int  e      = e0 + half;
        const bool active = (e < N_EDGES);
        int u = 0, v = 0;
        float xu = 0.0f, xv = 0.0f;
        if (active) {
            u  = edges[2 * e];
            v  = edges[2 * e + 1];
            xu = x[u * DIM + d];
            xv = x[v * DIM + d];
        }
        float p = xu * xv;
        if (d == 0) p = -p;
        #pragma unroll
        for (int off = 16; off; off >>= 1)
            p += __shfl_xor(p, off, 32);

        const float inner  = fminf(p, -1.0000001f);
        const float zm1    = -inner - 1.0f;
        const float s      = sqrtf(zm1 * (zm1 + 2.0f));
        const float dist   = log1pf(zm1 + s);
        const float delta  = dist - L0;
        const float factor = -delta / (s + 1e-9f);

        if (active) {
            atomicAdd(&grad[u * DIM + d], factor * xv * Jd);
            atomicAdd(&grad[v * DIM + d], factor * xu * Jd);
            if (d == 0)
                energy += 0.5 * (double)delta * (double)delta;
        }
    }
    #pragma unroll
    for (int off = 32; off; off >>= 1)
        energy += __shfl_xor(energy, off, 64);
    __shared__ double s_e[4];
    if (lane == 0) s_e[tid >> 6] = energy;
    __syncthreads();
    if (tid == 0)
        atomicAdd(&out[0], (float)(s_e[0] + s_e[1] + s_e[2] + s_e[3]));
}

extern "C" void kernel_launch(void* const* d_in, const int* in_sizes, int n_in,
                              void* d_out, int out_size, void* d_ws, size_t ws_size,
                              hipStream_t stream) {
    const float* x     = (const float*)d_in[0];
    const int*   edges = (const int*)d_in[1];
    float*       out   = (float*)d_out;

    const size_t grad_bytes = (size_t)N_NODES * HDIM * sizeof(__half2); // 6.4 MB
    const size_t need       = grad_bytes + sizeof(float);               // + energy

    if (ws_size >= need) {
        __half2* grad_h    = (__half2*)d_ws;
        float*   energy_ws = (float*)((char*)d_ws + grad_bytes);

        // ---- preferred: single cooperative dispatch (no memset needed;
        //      phase A zeroes ws in-kernel) ----
        void* kargs[] = {
            (void*)&x, (void*)&edges, (void*)&grad_h,
            (void*)&energy_ws, (void*)&out
        };
        const hipError_t err = hipLaunchCooperativeKernel(
            (void*)fused_coop_kernel,
            dim3(COOP_BLOCKS), dim3(COOP_THREADS), kargs, 0, stream);

        if (err != hipSuccess) {
            // ---- fallback: proven 3-dispatch R0 path ----
            hipMemsetAsync(d_ws, 0, need, stream);   // grad ws + energy slot
            spring_edge_f16_kernel<<<4096, 256, 0, stream>>>(x, edges, grad_h,
                                                             energy_ws);
            convert_kernel<<<(N_NODES * HDIM + 255) / 256, 256, 0, stream>>>(
                grad_h, energy_ws, out);
        }
    } else {
        hipMemsetAsync(out, 0, (size_t)out_size * sizeof(float), stream);
        spring_edge_kernel<<<4096, 256, 0, stream>>>(x, edges, out);
    }
}

// Round 8
// 274.326 us; speedup vs baseline: 2.1788x; 2.1788x over previous
//
#include <hip/hip_runtime.h>
#include <hip/hip_fp16.h>
#include <math.h>

#define DIM      32
#define HDIM     16                // DIM/2 float2 / half2 pairs per row
#define N_NODES  100000
#define N_EDGES  1600000
#define L0       0.1f

// ---------------------------------------------------------------------------
// Proven best path (R0, 266us): fused edge kernel, f16-packed atomics,
// 2-edge software pipeline.  One QUARTER-wave (16 lanes) per edge.
//
// Roofline evidence (R0-R7): grad scatter = 3.2M random 64B-sector RMW
// touches = 204.8MB atomic stream at ~1.0 TB/s (RMW ~2x a plain store ->
// saturates the ~2.1 TB/s random-sector fabric alongside 148MB fetch).
// VALU floor ~126us fully overlapped.  Alternatives measured & eliminated:
// CSR gather (450), fixed-point u64 atomics (371), binned LDS gather x2
// (749/688), u-dedup bucket x2 (399/407), cooperative fusion (598 -- coop
// mode collapses atomic throughput to 0.4 TB/s despite 97% occupancy).
// ---------------------------------------------------------------------------
__global__ __launch_bounds__(256) void spring_edge_f16_kernel(
    const float*  __restrict__ x,
    const int*    __restrict__ edges,
    __half2*      __restrict__ grad_h,     // N_NODES*HDIM half2 (ws)
    float*        __restrict__ energy_ws)  // 1 float (ws, pre-zeroed)
{
    const int tid   = threadIdx.x;
    const int lane  = tid & 63;
    const int k     = lane & 15;        // float2 pair index 0..15
    const int quad  = lane >> 4;        // which of the wave's 4 edges
    const int qId   = ((blockIdx.x * blockDim.x + tid) >> 6) * 4 + quad;
    const int nQuad = ((gridDim.x * blockDim.x) >> 6) * 4;

    const float2* __restrict__ x2 = (const float2*)x;
    const float Jx = (k == 0) ? -1.0f : 1.0f;   // J on dim0 = lane0 .x

    double energy = 0.0;

    for (int e0 = qId; e0 < N_EDGES; e0 += 2 * nQuad) {
        const int  e1 = e0 + nQuad;
        const bool a1 = (e1 < N_EDGES);

        // ---- issue all loads for both edges up front (6 vmem ops) ----
        const int2 ev0 = ((const int2*)edges)[e0];
        const int2 ev1 = a1 ? ((const int2*)edges)[e1] : make_int2(0, 0);
        const float2 xu0 = x2[ev0.x * HDIM + k];    // 16 lanes x 8B = 128B row
        const float2 xv0 = x2[ev0.y * HDIM + k];
        const float2 xu1 = x2[ev1.x * HDIM + k];
        const float2 xv1 = x2[ev1.y * HDIM + k];

        // ---- two independent dot-product reduces (interleaved) ----
        float p0 = Jx * xu0.x * xv0.x + xu0.y * xv0.y;
        float p1 = Jx * xu1.x * xv1.x + xu1.y * xv1.y;
        #pragma unroll
        for (int off = 8; off; off >>= 1) {
            p0 += __shfl_xor(p0, off, 16);
            p1 += __shfl_xor(p1, off, 16);
        }

        // ---- chain 0 ----
        {
            const float inner = fminf(p0, -1.0000001f);
            const float zm1   = -inner - 1.0f;
            const float s     = sqrtf(zm1 * (zm1 + 2.0f));
            const float dist  = log1pf(zm1 + s);
            const float delta = dist - L0;
            const float f     = -delta / (s + 1e-9f);
            unsafeAtomicAdd(&grad_h[ev0.x * HDIM + k],
                            __floats2half2_rn(f * Jx * xv0.x, f * xv0.y));
            unsafeAtomicAdd(&grad_h[ev0.y * HDIM + k],
                            __floats2half2_rn(f * Jx * xu0.x, f * xu0.y));
            if (k == 0) energy += 0.5 * (double)delta * (double)delta;
        }
        // ---- chain 1 ----
        if (a1) {
            const float inner = fminf(p1, -1.0000001f);
            const float zm1   = -inner - 1.0f;
            const float s     = sqrtf(zm1 * (zm1 + 2.0f));
            const float dist  = log1pf(zm1 + s);
            const float delta = dist - L0;
            const float f     = -delta / (s + 1e-9f);
            unsafeAtomicAdd(&grad_h[ev1.x * HDIM + k],
                            __floats2half2_rn(f * Jx * xv1.x, f * xv1.y));
            unsafeAtomicAdd(&grad_h[ev1.y * HDIM + k],
                            __floats2half2_rn(f * Jx * xu1.x, f * xu1.y));
            if (k == 0) energy += 0.5 * (double)delta * (double)delta;
        }
    }

    // lanes 0,16,32,48 hold energy; butterfly over full wave, block reduce
    #pragma unroll
    for (int off = 32; off; off >>= 1)
        energy += __shfl_xor(energy, off, 64);

    __shared__ double s_e[4];
    if (lane == 0) s_e[tid >> 6] = energy;
    __syncthreads();
    if (tid == 0)
        atomicAdd(energy_ws, (float)(s_e[0] + s_e[1] + s_e[2] + s_e[3]));
}

// ---------------------------------------------------------------------------
// f16 ws -> f32 grad (vectorized: 4 half2 in, 2 float4 out per thread),
// plus energy ws -> out[0].  Writes every element of d_out -> no out memset.
// ---------------------------------------------------------------------------
__global__ __launch_bounds__(256) void convert_kernel(
    const __half2* __restrict__ grad_h,
    const float*   __restrict__ energy_ws,
    float*         __restrict__ out)
{
    const int i = blockIdx.x * 256 + threadIdx.x;     // over N_NODES*HDIM/4
    if (i < N_NODES * HDIM / 4) {
        const __half2* g = grad_h + 4 * i;
        const float2 f0 = __half22float2(g[0]);
        const float2 f1 = __half22float2(g[1]);
        const float2 f2 = __half22float2(g[2]);
        const float2 f3 = __half22float2(g[3]);
        float* o = out + 1 + 8 * i;
        *reinterpret_cast<float4*>(o)     = make_float4(f0.x, f0.y, f1.x, f1.y);
        *reinterpret_cast<float4*>(o + 4) = make_float4(f2.x, f2.y, f3.x, f3.y);
    }
    if (i == 0) out[0] = *energy_ws;
}

// ---------------------------------------------------------------------------
// Fallback (ws too small): R1 fused kernel, known-correct at 505 us.
// ---------------------------------------------------------------------------
__global__ __launch_bounds__(256) void spring_edge_kernel(
    const float* __restrict__ x,
    const int*   __restrict__ edges,
    float*       __restrict__ out)
{
    const int tid    = threadIdx.x;
    const int lane   = tid & 63;
    const int d      = lane & 31;
    const int half   = lane >> 5;
    const int waveId = (blockIdx.x * blockDim.x + tid) >> 6;
    const int nWaves = (gridDim.x * blockDim.x) >> 6;

    float* __restrict__ grad = out + 1;
    const float Jd = (d == 0) ? -1.0f : 1.0f;
    double energy = 0.0;

    for (int e0 = waveId * 2; e0 < N_EDGES; e0 += nWaves * 2) {
        const int  e      = e0 + half;
        const bool active = (e < N_EDGES);
        int u = 0, v = 0;
        float xu = 0.0f, xv = 0.0f;
        if (active) {
            u  = edges[2 * e];
            v  = edges[2 * e + 1];
            xu = x[u * DIM + d];
            xv = x[v * DIM + d];
        }
        float p = xu * xv;
        if (d == 0) p = -p;
        #pragma unroll
        for (int off = 16; off; off >>= 1)
            p += __shfl_xor(p, off, 32);

        const float inner  = fminf(p, -1.0000001f);
        const float zm1    = -inner - 1.0f;
        const float s      = sqrtf(zm1 * (zm1 + 2.0f));
        const float dist   = log1pf(zm1 + s);
        const float delta  = dist - L0;
        const float factor = -delta / (s + 1e-9f);

        if (active) {
            atomicAdd(&grad[u * DIM + d], factor * xv * Jd);
            atomicAdd(&grad[v * DIM + d], factor * xu * Jd);
            if (d == 0)
                energy += 0.5 * (double)delta * (double)delta;
        }
    }
    #pragma unroll
    for (int off = 32; off; off >>= 1)
        energy += __shfl_xor(energy, off, 64);
    __shared__ double s_e[4];
    if (lane == 0) s_e[tid >> 6] = energy;
    __syncthreads();
    if (tid == 0)
        atomicAdd(&out[0], (float)(s_e[0] + s_e[1] + s_e[2] + s_e[3]));
}

extern "C" void kernel_launch(void* const* d_in, const int* in_sizes, int n_in,
                              void* d_out, int out_size, void* d_ws, size_t ws_size,
                              hipStream_t stream) {
    const float* x     = (const float*)d_in[0];
    const int*   edges = (const int*)d_in[1];
    float*       out   = (float*)d_out;

    const size_t grad_bytes = (size_t)N_NODES * HDIM * sizeof(__half2); // 6.4 MB
    const size_t need       = grad_bytes + sizeof(float);               // + energy

    if (ws_size >= need) {
        __half2* grad_h    = (__half2*)d_ws;
        float*   energy_ws = (float*)((char*)d_ws + grad_bytes);

        hipMemsetAsync(d_ws, 0, need, stream);   // grad ws + energy slot
        spring_edge_f16_kernel<<<4096, 256, 0, stream>>>(x, edges, grad_h,
                                                         energy_ws);
        convert_kernel<<<(N_NODES * HDIM / 4 + 255) / 256, 256, 0, stream>>>(
            grad_h, energy_ws, out);
    } else {
        hipMemsetAsync(out, 0, (size_t)out_size * sizeof(float), stream);
        spring_edge_kernel<<<4096, 256, 0, stream>>>(x, edges, out);
    }
}